// Round 8
// baseline (460.610 us; speedup 1.0000x reference)
//
#include <hip/hip_runtime.h>
#include <hip/hip_bf16.h>
#include <hip/hip_cooperative_groups.h>
#include <math.h>

namespace cg = cooperative_groups;

#define NEG_SLOPE 0.2f

__device__ __forceinline__ float lrelu(float v) {
    return v > 0.0f ? v : NEG_SLOPE * v;
}

__device__ __forceinline__ float wred_sum(float v) {
    #pragma unroll
    for (int d = 32; d; d >>= 1) v += __shfl_xor(v, d);
    return v;
}

__device__ __forceinline__ unsigned short f2bf(float f) {  // RNE f32->bf16
    unsigned u = __float_as_uint(f);
    return (unsigned short)((u + 0x7FFFu + ((u >> 16) & 1u)) >> 16);
}

__device__ __forceinline__ void bf8_fma(float* acc, uint4 u, float w) {
    acc[0] += w * __uint_as_float(u.x << 16);
    acc[1] += w * __uint_as_float(u.x & 0xFFFF0000u);
    acc[2] += w * __uint_as_float(u.y << 16);
    acc[3] += w * __uint_as_float(u.y & 0xFFFF0000u);
    acc[4] += w * __uint_as_float(u.z << 16);
    acc[5] += w * __uint_as_float(u.z & 0xFFFF0000u);
    acc[6] += w * __uint_as_float(u.w << 16);
    acc[7] += w * __uint_as_float(u.w & 0xFFFF0000u);
}

// ---------------------------------------------------------------------------
// Whole CSR build in ONE cooperative kernel:
//   P0 zero counts | P1 hist+rank | P2 hierarchical exclusive scan | P3 scatter
// Fixes vs round 7: (a) P2c guards read/write/scan-contribution with i < c1
// (was i < n4: cross-chunk stomp race); (b) offsets[N] = E written in P0
// (scan only covers indices < 4*n4; when N%4==0 that misses offsets[N]).
// ---------------------------------------------------------------------------
__global__ __launch_bounds__(256) void k_csr(const int* __restrict__ src,
                                             const int* __restrict__ dst,
                                             int E, int e4, int N,
                                             int* __restrict__ counts,
                                             int* __restrict__ offsets,
                                             int* __restrict__ rank,
                                             int* __restrict__ csr_src,
                                             int* __restrict__ partials) {
    cg::grid_group grid = cg::this_grid();
    const int tid = blockIdx.x * blockDim.x + threadIdx.x;
    const int nth = gridDim.x * blockDim.x;
    const int lane = threadIdx.x & 63;
    const int wv = threadIdx.x >> 6;
    const int n4 = (N + 3) >> 2;

    __shared__ int ws[4];
    __shared__ int sbase[4];
    __shared__ int scarry;

    // P0: zero counts (padded region included); pin offsets[N] = E
    for (int i = tid; i < n4; i += nth) ((int4*)counts)[i] = make_int4(0, 0, 0, 0);
    if (tid == 0) offsets[N] = E;
    grid.sync();

    // P1: histogram + rank (atomic return value = rank within dst segment)
    for (int i = tid; i < e4; i += nth) {
        int4 d = ((const int4*)dst)[i];
        int4 r;
        r.x = atomicAdd(&counts[d.x], 1);
        r.y = atomicAdd(&counts[d.y], 1);
        r.z = atomicAdd(&counts[d.z], 1);
        r.w = atomicAdd(&counts[d.w], 1);
        ((int4*)rank)[i] = r;
    }
    for (int j = (e4 << 2) + tid; j < E; j += nth)
        rank[j] = atomicAdd(&counts[dst[j]], 1);
    grid.sync();

    // P2a: per-block sum over its contiguous chunk of counts
    const int NB = gridDim.x;
    const int chunk4 = (n4 + NB - 1) / NB;
    const int c0 = min(blockIdx.x * chunk4, n4);
    const int c1 = min(c0 + chunk4, n4);
    {
        int lsum = 0;
        for (int i = c0 + (int)threadIdx.x; i < c1; i += 256) {
            int4 c = ((const int4*)counts)[i];
            lsum += c.x + c.y + c.z + c.w;
        }
        #pragma unroll
        for (int d = 32; d; d >>= 1) lsum += __shfl_xor(lsum, d);
        if (lane == 0) ws[wv] = lsum;
        __syncthreads();
        if (threadIdx.x == 0) partials[blockIdx.x] = ws[0] + ws[1] + ws[2] + ws[3];
    }
    grid.sync();

    // P2b: block 0 exclusive-scans partials[0..NB)
    if (blockIdx.x == 0) {
        const int npt = (NB + 255) >> 8;  // partials per thread (<= 8)
        int b = (int)threadIdx.x * npt;
        int v[8];
        int tot = 0;
        #pragma unroll
        for (int k = 0; k < 8; ++k) {
            if (k < npt) {
                v[k] = (b + k < NB) ? partials[b + k] : 0;
                tot += v[k];
            }
        }
        int x = tot;
        #pragma unroll
        for (int d = 1; d < 64; d <<= 1) {
            int y = __shfl_up(x, d);
            if (lane >= d) x += y;
        }
        if (lane == 63) ws[wv] = x;
        __syncthreads();
        if (threadIdx.x == 0) {
            int run = 0;
            #pragma unroll
            for (int k = 0; k < 4; ++k) { sbase[k] = run; run += ws[k]; }
        }
        __syncthreads();
        int excl = sbase[wv] + (x - tot);
        #pragma unroll
        for (int k = 0; k < 8; ++k) {
            if (k < npt) {
                if (b + k < NB) partials[b + k] = excl;
                excl += v[k];
            }
        }
    }
    grid.sync();

    // P2c: per-block exclusive scan of its OWN chunk only (i < c1 guard),
    // carry = scanned partial. Out-of-chunk lanes contribute 0 but still
    // execute the shfl scan (wave-uniform trip count).
    {
        if (threadIdx.x == 0) scarry = partials[blockIdx.x];
        __syncthreads();
        for (int base = c0; base < c1; base += 256) {
            int i = base + (int)threadIdx.x;
            bool in = (i < c1);
            int4 c = in ? ((const int4*)counts)[i] : make_int4(0, 0, 0, 0);
            int p1 = c.x, p2 = p1 + c.y, p3 = p2 + c.z, tot = p3 + c.w;
            int x = tot;
            #pragma unroll
            for (int d = 1; d < 64; d <<= 1) {
                int y = __shfl_up(x, d);
                if (lane >= d) x += y;
            }
            if (lane == 63) ws[wv] = x;
            __syncthreads();
            if (threadIdx.x == 0) {
                int run = scarry;
                #pragma unroll
                for (int k = 0; k < 4; ++k) { sbase[k] = run; run += ws[k]; }
                scarry = run;
            }
            __syncthreads();
            int excl = sbase[wv] + (x - tot);
            if (in)
                ((int4*)offsets)[i] = make_int4(excl, excl + p1, excl + p2, excl + p3);
            __syncthreads();  // ws/sbase reused next tile
        }
    }
    grid.sync();

    // P3: atomic-free scatter, position = offsets[dst] + rank
    for (int i = tid; i < e4; i += nth) {
        int4 s = ((const int4*)src)[i];
        int4 d = ((const int4*)dst)[i];
        int4 r = ((const int4*)rank)[i];
        csr_src[offsets[d.x] + r.x] = s.x;
        csr_src[offsets[d.y] + r.y] = s.y;
        csr_src[offsets[d.z] + r.z] = s.z;
        csr_src[offsets[d.w] + r.w] = s.w;
    }
    for (int j = (e4 << 2) + tid; j < E; j += nth)
        csr_src[offsets[dst[j]] + rank[j]] = src[j];
}

// ---- Fallback split-kernel CSR build (round-6 proven path) ----
__global__ void k_zero4(int* __restrict__ p, int n4) {
    int i = blockIdx.x * blockDim.x + threadIdx.x;
    if (i < n4) ((int4*)p)[i] = make_int4(0, 0, 0, 0);
}

__global__ void k_hist_rank(const int* __restrict__ dst, int E,
                            int* __restrict__ counts, int* __restrict__ rank) {
    int i = blockIdx.x * blockDim.x + threadIdx.x;
    int base = i << 2;
    if (base + 3 < E) {
        int4 d = ((const int4*)dst)[i];
        int4 r;
        r.x = atomicAdd(&counts[d.x], 1);
        r.y = atomicAdd(&counts[d.y], 1);
        r.z = atomicAdd(&counts[d.z], 1);
        r.w = atomicAdd(&counts[d.w], 1);
        ((int4*)rank)[i] = r;
    } else {
        for (int j = base; j < E; ++j) rank[j] = atomicAdd(&counts[dst[j]], 1);
    }
}

__global__ void k_hist_rank_s(const int* __restrict__ dst, int E,
                              int* __restrict__ counts, int* __restrict__ rank) {
    int i = blockIdx.x * blockDim.x + threadIdx.x;
    if (i < E) rank[i] = atomicAdd(&counts[dst[i]], 1);
}

__global__ __launch_bounds__(1024) void k_scan(const int* __restrict__ counts,
                                               int* __restrict__ offsets, int n) {
    __shared__ int wsums[16];
    __shared__ int carry_sh;
    int tid = threadIdx.x;
    int lane = tid & 63;
    int wv = tid >> 6;
    if (tid == 0) carry_sh = 0;
    __syncthreads();
    int n4 = (n + 3) >> 2;
    for (int base = 0; base < n4; base += 1024) {
        int i = base + tid;
        int e0 = i << 2;
        int v0 = 0, v1 = 0, v2 = 0, v3 = 0;
        if (e0 + 3 < n) {
            int4 c = ((const int4*)counts)[i];
            v0 = c.x; v1 = c.y; v2 = c.z; v3 = c.w;
        } else if (e0 < n) {
            v0 = counts[e0];
            if (e0 + 1 < n) v1 = counts[e0 + 1];
            if (e0 + 2 < n) v2 = counts[e0 + 2];
        }
        int p1 = v0, p2 = p1 + v1, p3 = p2 + v2, tot = p3 + v3;
        int x = tot;
        #pragma unroll
        for (int d = 1; d < 64; d <<= 1) {
            int y = __shfl_up(x, d);
            if (lane >= d) x += y;
        }
        if (lane == 63) wsums[wv] = x;
        __syncthreads();
        if (wv == 0) {
            int s = (lane < 16) ? wsums[lane] : 0;
            #pragma unroll
            for (int d = 1; d < 16; d <<= 1) {
                int y = __shfl_up(s, d);
                if (lane >= d) s += y;
            }
            if (lane < 16) wsums[lane] = s;
        }
        __syncthreads();
        int excl = carry_sh + (wv > 0 ? wsums[wv - 1] : 0) + (x - tot);
        if (e0 + 3 < n) {
            ((int4*)offsets)[i] = make_int4(excl, excl + p1, excl + p2, excl + p3);
        } else if (e0 < n) {
            offsets[e0] = excl;
            if (e0 + 1 < n) offsets[e0 + 1] = excl + p1;
            if (e0 + 2 < n) offsets[e0 + 2] = excl + p2;
        }
        __syncthreads();
        if (tid == 0) carry_sh += wsums[15];
        __syncthreads();
    }
    if (tid == 0) offsets[n] = carry_sh;
}

__global__ void k_scatter(const int* __restrict__ src, const int* __restrict__ dst,
                          const int* __restrict__ rank, const int* __restrict__ offsets,
                          int E, int* __restrict__ csr_src) {
    int i = blockIdx.x * blockDim.x + threadIdx.x;
    int base = i << 2;
    if (base + 3 < E) {
        int4 s = ((const int4*)src)[i];
        int4 d = ((const int4*)dst)[i];
        int4 r = ((const int4*)rank)[i];
        csr_src[offsets[d.x] + r.x] = s.x;
        csr_src[offsets[d.y] + r.y] = s.y;
        csr_src[offsets[d.z] + r.z] = s.z;
        csr_src[offsets[d.w] + r.w] = s.w;
    } else {
        for (int j = base; j < E; ++j) csr_src[offsets[dst[j]] + rank[j]] = src[j];
    }
}

__global__ void k_scatter_s(const int* __restrict__ src, const int* __restrict__ dst,
                            const int* __restrict__ rank, const int* __restrict__ offsets,
                            int E, int* __restrict__ csr_src) {
    int i = blockIdx.x * blockDim.x + threadIdx.x;
    if (i < E) csr_src[offsets[dst[i]] + rank[i]] = src[i];
}

// XL_bf16[n,128] = X[n,128] @ W[128,128] (f32 math, bf16 store), fused
// a_s/a_d epilogue (computed from f32 accumulators).
// Block: 256 thr, tile 128 rows x 128 cols, 8x8 register blocking, K halves
// of 64. X tile staged TRANSPOSED (k-major) with XOR swizzle
// r' = r ^ (((k>>2)&7)<<2): staging writes 2-way (free, m136), xv reads
// conflict-free, 16B alignment preserved (swizzle only touches elem bits 2-4).
__global__ __launch_bounds__(256) void k_gemm_attn(const float* __restrict__ X,
                                                   const float* __restrict__ W,
                                                   const float* __restrict__ att_s,
                                                   const float* __restrict__ att_d,
                                                   unsigned short* __restrict__ XLb,
                                                   float* __restrict__ a_s,
                                                   float* __restrict__ a_d, int n) {
    __shared__ float XT[64 * 128];  // 32 KB, XT[k*128 + (r^sw(k))]
    __shared__ float Wl[64 * 128];  // 32 KB, Wl[k*128 + col]
    int tid = threadIdx.x;
    int row0 = blockIdx.x * 128;
    int c = tid & 15;   // col group: cols c*4..+3 and 64+c*4..+3
    int rg = tid >> 4;  // row group: rows rg*8..rg*8+7

    float acc[8][8] = {};
    for (int kb = 0; kb < 128; kb += 64) {
        __syncthreads();
        {   // stage W K-half (straight copy, coalesced, conflict-free)
            const float4* W4 = (const float4*)(W + (size_t)kb * 128);
            float4* Wl4 = (float4*)Wl;
            #pragma unroll
            for (int i = 0; i < 8; ++i) Wl4[tid + i * 256] = W4[tid + i * 256];
        }
        {   // stage X transposed + swizzled
            #pragma unroll
            for (int it = 0; it < 8; ++it) {
                int idx = tid + it * 256;  // 0..2047
                int r = idx >> 4;          // 0..127
                int kq = idx & 15;         // float4 index within K-half
                int gr = row0 + r;
                float4 v = (gr < n) ? ((const float4*)X)[(size_t)gr * 32 + (kb >> 2) + kq]
                                    : make_float4(0.f, 0.f, 0.f, 0.f);
                int rs = r ^ ((kq & 7) << 2);
                float* dstp = &XT[(kq * 4) * 128 + rs];
                dstp[0 * 128] = v.x;
                dstp[1 * 128] = v.y;
                dstp[2 * 128] = v.z;
                dstp[3 * 128] = v.w;
            }
        }
        __syncthreads();
        #pragma unroll 2
        for (int kk = 0; kk < 64; ++kk) {
            int sw = ((kk >> 2) & 7) << 2;
            const float* xt = &XT[kk * 128];
            float4 xa = *(const float4*)&xt[(rg * 8) ^ sw];
            float4 xb = *(const float4*)&xt[(rg * 8 + 4) ^ sw];
            const float* wr = &Wl[kk * 128];
            float4 wa = *(const float4*)&wr[c * 4];
            float4 wb = *(const float4*)&wr[64 + c * 4];
            float xv[8] = {xa.x, xa.y, xa.z, xa.w, xb.x, xb.y, xb.z, xb.w};
            float wv[8] = {wa.x, wa.y, wa.z, wa.w, wb.x, wb.y, wb.z, wb.w};
            #pragma unroll
            for (int i = 0; i < 8; ++i)
                #pragma unroll
                for (int j = 0; j < 8; ++j)
                    acc[i][j] += xv[i] * wv[j];
        }
    }

    // fused attention dots from f32 accumulators
    float4 as_a = ((const float4*)att_s)[c];
    float4 as_b = ((const float4*)att_s)[16 + c];
    float4 ad_a = ((const float4*)att_d)[c];
    float4 ad_b = ((const float4*)att_d)[16 + c];
    float asv[8] = {as_a.x, as_a.y, as_a.z, as_a.w, as_b.x, as_b.y, as_b.z, as_b.w};
    float adv[8] = {ad_a.x, ad_a.y, ad_a.z, ad_a.w, ad_b.x, ad_b.y, ad_b.z, ad_b.w};
    #pragma unroll
    for (int i = 0; i < 8; ++i) {
        float ps = 0.f, pd = 0.f;
        #pragma unroll
        for (int j = 0; j < 8; ++j) { ps += acc[i][j] * asv[j]; pd += acc[i][j] * adv[j]; }
        #pragma unroll
        for (int d = 1; d < 16; d <<= 1) { ps += __shfl_xor(ps, d); pd += __shfl_xor(pd, d); }
        int r = row0 + rg * 8 + i;
        if (c == 0 && r < n) { a_s[r] = ps; a_d[r] = pd; }
    }
    // bf16 store of XL (gather operand)
    #pragma unroll
    for (int i = 0; i < 8; ++i) {
        int r = row0 + rg * 8 + i;
        if (r < n) {
            unsigned p0 = ((unsigned)f2bf(acc[i][1]) << 16) | f2bf(acc[i][0]);
            unsigned p1 = ((unsigned)f2bf(acc[i][3]) << 16) | f2bf(acc[i][2]);
            unsigned p2 = ((unsigned)f2bf(acc[i][5]) << 16) | f2bf(acc[i][4]);
            unsigned p3 = ((unsigned)f2bf(acc[i][7]) << 16) | f2bf(acc[i][6]);
            uint2* o = (uint2*)(XLb + (size_t)r * 128);
            o[c] = make_uint2(p0, p1);       // cols c*4..c*4+3
            o[16 + c] = make_uint2(p2, p3);  // cols 64+c*4..+3
        }
    }
}

// One wave per dst node. No-max softmax (logits bounded, exp safe in f32).
// Four 16-lane groups process 4 edges/iter; each lane loads uint4 = 8 bf16
// channels (16B). Gather loop trip count is WAVE-UNIFORM with clamped shfl
// index (shfl from exec-masked lanes is undefined on CDNA). Tail (deg>64)
// has no shfl, so divergent trip counts are safe there.
__global__ __launch_bounds__(256) void k_aggregate(const unsigned short* __restrict__ xlb,
                                                   const float* __restrict__ a_s,
                                                   const float* __restrict__ a_d,
                                                   const int* __restrict__ csr_src,
                                                   const int* __restrict__ offsets,
                                                   const float* __restrict__ bias,
                                                   float* __restrict__ out, int n) {
    int wid = (blockIdx.x * blockDim.x + threadIdx.x) >> 6;
    int lane = threadIdx.x & 63;
    if (wid >= n) return;
    int beg = offsets[wid];
    int deg = offsets[wid + 1] - beg;
    float a_dn = a_d[wid];
    float w_self = __expf(lrelu(a_s[wid] + a_dn));

    int s_l = 0;
    float w_l = 0.0f;
    if (lane < deg) {
        s_l = csr_src[beg + lane];
        w_l = __expf(lrelu(a_s[s_l] + a_dn));
    }
    float zl = w_l;
    for (int j = 64 + lane; j < deg; j += 64) {
        int s = csr_src[beg + j];
        zl += __expf(lrelu(a_s[s] + a_dn));
    }
    float z = wred_sum(zl) + w_self;
    float inv = 1.0f / (z + 1e-16f);

    int qw = lane >> 4, ql = lane & 15;
    const uint4* xb4 = (const uint4*)xlb;  // row = 16 x uint4 (256B)
    float acc[8] = {};
    if (qw == 0) {  // self loop handled by group 0
        uint4 u = xb4[(size_t)wid * 16 + ql];
        bf8_fma(acc, u, w_self);
    }
    int jmax = deg < 64 ? deg : 64;
    int nt = (jmax + 3) >> 2;  // uniform trip count across the wave
    for (int t = 0; t < nt; ++t) {
        int j = (t << 2) + qw;
        int jj = j < jmax ? j : 0;  // clamped: shfl always well-defined
        float wj = __shfl(w_l, jj);
        int sj = __shfl(s_l, jj);
        if (j < jmax) {
            uint4 u = xb4[(size_t)sj * 16 + ql];
            bf8_fma(acc, u, wj);
        }
    }
    for (int j = 64 + qw; j < deg; j += 4) {  // rare tail, no shfl
        int sj = csr_src[beg + j];
        float wj = __expf(lrelu(a_s[sj] + a_dn));
        uint4 u = xb4[(size_t)sj * 16 + ql];
        bf8_fma(acc, u, wj);
    }
    #pragma unroll
    for (int k = 0; k < 8; ++k) {
        acc[k] += __shfl_xor(acc[k], 16);
        acc[k] += __shfl_xor(acc[k], 32);
    }
    if (qw == 0) {
        float4 b0 = ((const float4*)bias)[ql * 2];
        float4 b1 = ((const float4*)bias)[ql * 2 + 1];
        float4 r0, r1;
        r0.x = fmaxf(acc[0] * inv + b0.x, 0.0f);
        r0.y = fmaxf(acc[1] * inv + b0.y, 0.0f);
        r0.z = fmaxf(acc[2] * inv + b0.z, 0.0f);
        r0.w = fmaxf(acc[3] * inv + b0.w, 0.0f);
        r1.x = fmaxf(acc[4] * inv + b1.x, 0.0f);
        r1.y = fmaxf(acc[5] * inv + b1.y, 0.0f);
        r1.z = fmaxf(acc[6] * inv + b1.z, 0.0f);
        r1.w = fmaxf(acc[7] * inv + b1.w, 0.0f);
        ((float4*)out)[(size_t)wid * 32 + ql * 2] = r0;
        ((float4*)out)[(size_t)wid * 32 + ql * 2 + 1] = r1;
    }
}

extern "C" void kernel_launch(void* const* d_in, const int* in_sizes, int n_in,
                              void* d_out, int out_size, void* d_ws, size_t ws_size,
                              hipStream_t stream) {
    const float* x = (const float*)d_in[0];
    const int* edges = (const int*)d_in[1];
    const float* W1 = (const float*)d_in[2];
    const float* att_s1 = (const float*)d_in[3];
    const float* att_d1 = (const float*)d_in[4];
    const float* b1 = (const float*)d_in[5];
    const float* W2 = (const float*)d_in[6];
    const float* att_s2 = (const float*)d_in[7];
    const float* att_d2 = (const float*)d_in[8];
    const float* b2 = (const float*)d_in[9];

    const int N = in_sizes[0] / 128;
    const int E = in_sizes[1] / 2;
    const int* e_src = edges;
    const int* e_dst = edges + E;

    char* w = (char*)d_ws;
    auto carve = [&](size_t bytes) {
        char* p = w;
        w += (bytes + 255) & ~(size_t)255;
        return p;
    };
    const int n4 = (N + 3) >> 2;
    int* counts = (int*)carve((size_t)n4 * 16);           // padded to int4
    int* offsets = (int*)carve((size_t)(n4 * 4 + 8) * 4); // covers offsets[N]
    int* rank = (int*)carve((size_t)E * 4);
    int* csr_src = (int*)carve((size_t)E * 4);
    int* partials = (int*)carve(2048 * 4);
    float* a_s = (float*)carve((size_t)N * 4);
    float* a_d = (float*)carve((size_t)N * 4);
    unsigned short* xlb = (unsigned short*)carve((size_t)N * 128 * 2);
    float* h = (float*)carve((size_t)N * 128 * 4);

    float* out = (float*)d_out;

    // --- CSR build: one cooperative kernel; fallback to split path if the
    // cooperative launch reports failure (e.g. unsupported under capture) ---
    int e4 = ((E & 3) == 0 && ((((uintptr_t)e_dst) & 15) == 0) &&
              ((((uintptr_t)e_src) & 15) == 0)) ? (E >> 2) : 0;
    int Ev = E, Nv = N;
    void* args[] = {(void*)&e_src, (void*)&e_dst, (void*)&Ev, (void*)&e4, (void*)&Nv,
                    (void*)&counts, (void*)&offsets, (void*)&rank,
                    (void*)&csr_src, (void*)&partials};
    hipError_t cerr = hipLaunchCooperativeKernel((const void*)k_csr, dim3(512), dim3(256),
                                                 args, 0, stream);
    if (cerr != hipSuccess) {
        k_zero4<<<(n4 + 255) / 256, 256, 0, stream>>>(counts, n4);
        if (e4 > 0) {
            int qb = (e4 + 255) / 256;
            k_hist_rank<<<qb, 256, 0, stream>>>(e_dst, E, counts, rank);
            k_scan<<<1, 1024, 0, stream>>>(counts, offsets, N);
            k_scatter<<<qb, 256, 0, stream>>>(e_src, e_dst, rank, offsets, E, csr_src);
        } else {
            int sb = (E + 255) / 256;
            k_hist_rank_s<<<sb, 256, 0, stream>>>(e_dst, E, counts, rank);
            k_scan<<<1, 1024, 0, stream>>>(counts, offsets, N);
            k_scatter_s<<<sb, 256, 0, stream>>>(e_src, e_dst, rank, offsets, E, csr_src);
        }
    }

    int gemm_blocks = (N + 127) / 128;
    int wave_blocks = (N * 64 + 255) / 256;

    // layer 1
    k_gemm_attn<<<gemm_blocks, 256, 0, stream>>>(x, W1, att_s1, att_d1, xlb, a_s, a_d, N);
    k_aggregate<<<wave_blocks, 256, 0, stream>>>(xlb, a_s, a_d, csr_src, offsets, b1, h, N);

    // layer 2 (xlb reused; agg1 finishes before gemm2 overwrites it)
    k_gemm_attn<<<gemm_blocks, 256, 0, stream>>>(h, W2, att_s2, att_d2, xlb, a_s, a_d, N);
    k_aggregate<<<wave_blocks, 256, 0, stream>>>(xlb, a_s, a_d, csr_src, offsets, b2, out, N);
}

// Round 9
// 216.344 us; speedup vs baseline: 2.1291x; 2.1291x over previous
//
#include <hip/hip_runtime.h>
#include <hip/hip_bf16.h>
#include <math.h>

#define NEG_SLOPE 0.2f

__device__ __forceinline__ float lrelu(float v) {
    return v > 0.0f ? v : NEG_SLOPE * v;
}

__device__ __forceinline__ float wred_sum(float v) {
    #pragma unroll
    for (int d = 32; d; d >>= 1) v += __shfl_xor(v, d);
    return v;
}

__device__ __forceinline__ unsigned short f2bf(float f) {  // RNE f32->bf16
    unsigned u = __float_as_uint(f);
    return (unsigned short)((u + 0x7FFFu + ((u >> 16) & 1u)) >> 16);
}

__device__ __forceinline__ void bf8_fma(float* acc, uint4 u, float w) {
    acc[0] += w * __uint_as_float(u.x << 16);
    acc[1] += w * __uint_as_float(u.x & 0xFFFF0000u);
    acc[2] += w * __uint_as_float(u.y << 16);
    acc[3] += w * __uint_as_float(u.y & 0xFFFF0000u);
    acc[4] += w * __uint_as_float(u.z << 16);
    acc[5] += w * __uint_as_float(u.z & 0xFFFF0000u);
    acc[6] += w * __uint_as_float(u.w << 16);
    acc[7] += w * __uint_as_float(u.w & 0xFFFF0000u);
}

// ---- Split-kernel CSR build (round-6 proven path; cooperative k_csr was
// 300 us — grid.sync() across 8 XCDs costs ~50 us/barrier, launches ~2 us) ----
__global__ void k_zero4(int* __restrict__ p, int n4) {
    int i = blockIdx.x * blockDim.x + threadIdx.x;
    if (i < n4) ((int4*)p)[i] = make_int4(0, 0, 0, 0);
}

// Histogram + rank capture: atomicAdd return value IS the edge's rank
// within its dst segment. 4 edges/thread for memory-level parallelism.
__global__ void k_hist_rank(const int* __restrict__ dst, int E,
                            int* __restrict__ counts, int* __restrict__ rank) {
    int i = blockIdx.x * blockDim.x + threadIdx.x;
    int base = i << 2;
    if (base + 3 < E) {
        int4 d = ((const int4*)dst)[i];
        int4 r;
        r.x = atomicAdd(&counts[d.x], 1);
        r.y = atomicAdd(&counts[d.y], 1);
        r.z = atomicAdd(&counts[d.z], 1);
        r.w = atomicAdd(&counts[d.w], 1);
        ((int4*)rank)[i] = r;
    } else {
        for (int j = base; j < E; ++j) rank[j] = atomicAdd(&counts[dst[j]], 1);
    }
}

__global__ void k_hist_rank_s(const int* __restrict__ dst, int E,
                              int* __restrict__ counts, int* __restrict__ rank) {
    int i = blockIdx.x * blockDim.x + threadIdx.x;
    if (i < E) rank[i] = atomicAdd(&counts[dst[i]], 1);
}

// Single-block exclusive scan, 4 elements/thread -> offsets[0..n].
__global__ __launch_bounds__(1024) void k_scan(const int* __restrict__ counts,
                                               int* __restrict__ offsets, int n) {
    __shared__ int wsums[16];
    __shared__ int carry_sh;
    int tid = threadIdx.x;
    int lane = tid & 63;
    int wv = tid >> 6;
    if (tid == 0) carry_sh = 0;
    __syncthreads();
    int n4 = (n + 3) >> 2;
    for (int base = 0; base < n4; base += 1024) {
        int i = base + tid;
        int e0 = i << 2;
        int v0 = 0, v1 = 0, v2 = 0, v3 = 0;
        if (e0 + 3 < n) {
            int4 c = ((const int4*)counts)[i];
            v0 = c.x; v1 = c.y; v2 = c.z; v3 = c.w;
        } else if (e0 < n) {
            v0 = counts[e0];
            if (e0 + 1 < n) v1 = counts[e0 + 1];
            if (e0 + 2 < n) v2 = counts[e0 + 2];
        }
        int p1 = v0, p2 = p1 + v1, p3 = p2 + v2, tot = p3 + v3;
        int x = tot;
        #pragma unroll
        for (int d = 1; d < 64; d <<= 1) {
            int y = __shfl_up(x, d);
            if (lane >= d) x += y;
        }
        if (lane == 63) wsums[wv] = x;
        __syncthreads();
        if (wv == 0) {
            int s = (lane < 16) ? wsums[lane] : 0;
            #pragma unroll
            for (int d = 1; d < 16; d <<= 1) {
                int y = __shfl_up(s, d);
                if (lane >= d) s += y;
            }
            if (lane < 16) wsums[lane] = s;
        }
        __syncthreads();
        int excl = carry_sh + (wv > 0 ? wsums[wv - 1] : 0) + (x - tot);
        if (e0 + 3 < n) {
            ((int4*)offsets)[i] = make_int4(excl, excl + p1, excl + p2, excl + p3);
        } else if (e0 < n) {
            offsets[e0] = excl;
            if (e0 + 1 < n) offsets[e0 + 1] = excl + p1;
            if (e0 + 2 < n) offsets[e0 + 2] = excl + p2;
        }
        __syncthreads();
        if (tid == 0) carry_sh += wsums[15];
        __syncthreads();
    }
    if (tid == 0) offsets[n] = carry_sh;
}

// Atomic-free scatter: position = offsets[dst] + rank. 4 edges/thread.
__global__ void k_scatter(const int* __restrict__ src, const int* __restrict__ dst,
                          const int* __restrict__ rank, const int* __restrict__ offsets,
                          int E, int* __restrict__ csr_src) {
    int i = blockIdx.x * blockDim.x + threadIdx.x;
    int base = i << 2;
    if (base + 3 < E) {
        int4 s = ((const int4*)src)[i];
        int4 d = ((const int4*)dst)[i];
        int4 r = ((const int4*)rank)[i];
        csr_src[offsets[d.x] + r.x] = s.x;
        csr_src[offsets[d.y] + r.y] = s.y;
        csr_src[offsets[d.z] + r.z] = s.z;
        csr_src[offsets[d.w] + r.w] = s.w;
    } else {
        for (int j = base; j < E; ++j) csr_src[offsets[dst[j]] + rank[j]] = src[j];
    }
}

__global__ void k_scatter_s(const int* __restrict__ src, const int* __restrict__ dst,
                            const int* __restrict__ rank, const int* __restrict__ offsets,
                            int E, int* __restrict__ csr_src) {
    int i = blockIdx.x * blockDim.x + threadIdx.x;
    if (i < E) csr_src[offsets[dst[i]] + rank[i]] = src[i];
}

// XL_bf16[n,128] = X[n,128] @ W[128,128] (f32 math, bf16 store), fused
// a_s/a_d epilogue (computed from f32 accumulators).
// Block: 256 thr, tile 128 rows x 128 cols, 8x8 register blocking, K halves
// of 64. X tile staged TRANSPOSED (k-major) with XOR swizzle
// r' = r ^ (((k>>2)&7)<<2): staging writes 2-way (free), xv reads
// conflict-free, 16B alignment preserved (swizzle only touches elem bits 2-4).
__global__ __launch_bounds__(256) void k_gemm_attn(const float* __restrict__ X,
                                                   const float* __restrict__ W,
                                                   const float* __restrict__ att_s,
                                                   const float* __restrict__ att_d,
                                                   unsigned short* __restrict__ XLb,
                                                   float* __restrict__ a_s,
                                                   float* __restrict__ a_d, int n) {
    __shared__ float XT[64 * 128];  // 32 KB, XT[k*128 + (r^sw(k))]
    __shared__ float Wl[64 * 128];  // 32 KB, Wl[k*128 + col]
    int tid = threadIdx.x;
    int row0 = blockIdx.x * 128;
    int c = tid & 15;   // col group: cols c*4..+3 and 64+c*4..+3
    int rg = tid >> 4;  // row group: rows rg*8..rg*8+7

    float acc[8][8] = {};
    for (int kb = 0; kb < 128; kb += 64) {
        __syncthreads();
        {   // stage W K-half (straight copy, coalesced, conflict-free)
            const float4* W4 = (const float4*)(W + (size_t)kb * 128);
            float4* Wl4 = (float4*)Wl;
            #pragma unroll
            for (int i = 0; i < 8; ++i) Wl4[tid + i * 256] = W4[tid + i * 256];
        }
        {   // stage X transposed + swizzled
            #pragma unroll
            for (int it = 0; it < 8; ++it) {
                int idx = tid + it * 256;  // 0..2047
                int r = idx >> 4;          // 0..127
                int kq = idx & 15;         // float4 index within K-half
                int gr = row0 + r;
                float4 v = (gr < n) ? ((const float4*)X)[(size_t)gr * 32 + (kb >> 2) + kq]
                                    : make_float4(0.f, 0.f, 0.f, 0.f);
                int rs = r ^ ((kq & 7) << 2);
                float* dstp = &XT[(kq * 4) * 128 + rs];
                dstp[0 * 128] = v.x;
                dstp[1 * 128] = v.y;
                dstp[2 * 128] = v.z;
                dstp[3 * 128] = v.w;
            }
        }
        __syncthreads();
        #pragma unroll 2
        for (int kk = 0; kk < 64; ++kk) {
            int sw = ((kk >> 2) & 7) << 2;
            const float* xt = &XT[kk * 128];
            float4 xa = *(const float4*)&xt[(rg * 8) ^ sw];
            float4 xb = *(const float4*)&xt[(rg * 8 + 4) ^ sw];
            const float* wr = &Wl[kk * 128];
            float4 wa = *(const float4*)&wr[c * 4];
            float4 wb = *(const float4*)&wr[64 + c * 4];
            float xv[8] = {xa.x, xa.y, xa.z, xa.w, xb.x, xb.y, xb.z, xb.w};
            float wv[8] = {wa.x, wa.y, wa.z, wa.w, wb.x, wb.y, wb.z, wb.w};
            #pragma unroll
            for (int i = 0; i < 8; ++i)
                #pragma unroll
                for (int j = 0; j < 8; ++j)
                    acc[i][j] += xv[i] * wv[j];
        }
    }

    // fused attention dots from f32 accumulators
    float4 as_a = ((const float4*)att_s)[c];
    float4 as_b = ((const float4*)att_s)[16 + c];
    float4 ad_a = ((const float4*)att_d)[c];
    float4 ad_b = ((const float4*)att_d)[16 + c];
    float asv[8] = {as_a.x, as_a.y, as_a.z, as_a.w, as_b.x, as_b.y, as_b.z, as_b.w};
    float adv[8] = {ad_a.x, ad_a.y, ad_a.z, ad_a.w, ad_b.x, ad_b.y, ad_b.z, ad_b.w};
    #pragma unroll
    for (int i = 0; i < 8; ++i) {
        float ps = 0.f, pd = 0.f;
        #pragma unroll
        for (int j = 0; j < 8; ++j) { ps += acc[i][j] * asv[j]; pd += acc[i][j] * adv[j]; }
        #pragma unroll
        for (int d = 1; d < 16; d <<= 1) { ps += __shfl_xor(ps, d); pd += __shfl_xor(pd, d); }
        int r = row0 + rg * 8 + i;
        if (c == 0 && r < n) { a_s[r] = ps; a_d[r] = pd; }
    }
    // bf16 store of XL (gather operand)
    #pragma unroll
    for (int i = 0; i < 8; ++i) {
        int r = row0 + rg * 8 + i;
        if (r < n) {
            unsigned p0 = ((unsigned)f2bf(acc[i][1]) << 16) | f2bf(acc[i][0]);
            unsigned p1 = ((unsigned)f2bf(acc[i][3]) << 16) | f2bf(acc[i][2]);
            unsigned p2 = ((unsigned)f2bf(acc[i][5]) << 16) | f2bf(acc[i][4]);
            unsigned p3 = ((unsigned)f2bf(acc[i][7]) << 16) | f2bf(acc[i][6]);
            uint2* o = (uint2*)(XLb + (size_t)r * 128);
            o[c] = make_uint2(p0, p1);       // cols c*4..c*4+3
            o[16 + c] = make_uint2(p2, p3);  // cols 64+c*4..+3
        }
    }
}

// One wave per dst node. No-max softmax (logits bounded, exp safe in f32).
// Gather loop unrolled x2: four 16-lane groups each process edges t*8+qw and
// t*8+4+qw per iteration -> 8 outstanding uint4 gathers/wave (was 4).
// BRANCH-FREE inner body: shfl with clamped index (full wave active, always
// well-defined), weight zeroed for OOB slots, loads unconditional (OOB slot
// re-loads edge 0's row — L2-hit, exact since 0*v contributes nothing).
__global__ __launch_bounds__(256) void k_aggregate(const unsigned short* __restrict__ xlb,
                                                   const float* __restrict__ a_s,
                                                   const float* __restrict__ a_d,
                                                   const int* __restrict__ csr_src,
                                                   const int* __restrict__ offsets,
                                                   const float* __restrict__ bias,
                                                   float* __restrict__ out, int n) {
    int wid = (blockIdx.x * blockDim.x + threadIdx.x) >> 6;
    int lane = threadIdx.x & 63;
    if (wid >= n) return;
    int beg = offsets[wid];
    int deg = offsets[wid + 1] - beg;
    float a_dn = a_d[wid];
    float w_self = __expf(lrelu(a_s[wid] + a_dn));

    int s_l = 0;
    float w_l = 0.0f;
    if (lane < deg) {
        s_l = csr_src[beg + lane];
        w_l = __expf(lrelu(a_s[s_l] + a_dn));
    }
    float zl = w_l;
    for (int j = 64 + lane; j < deg; j += 64) {
        int s = csr_src[beg + j];
        zl += __expf(lrelu(a_s[s] + a_dn));
    }
    float z = wred_sum(zl) + w_self;
    float inv = 1.0f / (z + 1e-16f);

    int qw = lane >> 4, ql = lane & 15;
    const uint4* xb4 = (const uint4*)xlb;  // row = 16 x uint4 (256B)
    float acc[8] = {};
    if (qw == 0) {  // self loop handled by group 0
        uint4 u = xb4[(size_t)wid * 16 + ql];
        bf8_fma(acc, u, w_self);
    }
    int jmax = deg < 64 ? deg : 64;
    int nt = (jmax + 7) >> 3;  // uniform trip count across the wave
    for (int t = 0; t < nt; ++t) {
        int ja = (t << 3) + qw;
        int jb = ja + 4;
        int jca = ja < jmax ? ja : 0;  // clamped: shfl always well-defined
        int jcb = jb < jmax ? jb : 0;
        float wa = __shfl(w_l, jca);
        int sa = __shfl(s_l, jca);
        float wb = __shfl(w_l, jcb);
        int sb = __shfl(s_l, jcb);
        if (ja >= jmax) wa = 0.0f;     // OOB contributes exactly 0
        if (jb >= jmax) wb = 0.0f;
        uint4 ua = xb4[(size_t)sa * 16 + ql];  // unconditional: both loads
        uint4 ub = xb4[(size_t)sb * 16 + ql];  // in flight before the FMAs
        bf8_fma(acc, ua, wa);
        bf8_fma(acc, ub, wb);
    }
    for (int j = 64 + qw; j < deg; j += 4) {  // rare tail (deg > 64), no shfl
        int sj = csr_src[beg + j];
        float wj = __expf(lrelu(a_s[sj] + a_dn));
        uint4 u = xb4[(size_t)sj * 16 + ql];
        bf8_fma(acc, u, wj);
    }
    #pragma unroll
    for (int k = 0; k < 8; ++k) {
        acc[k] += __shfl_xor(acc[k], 16);
        acc[k] += __shfl_xor(acc[k], 32);
    }
    if (qw == 0) {
        float4 b0 = ((const float4*)bias)[ql * 2];
        float4 b1 = ((const float4*)bias)[ql * 2 + 1];
        float4 r0, r1;
        r0.x = fmaxf(acc[0] * inv + b0.x, 0.0f);
        r0.y = fmaxf(acc[1] * inv + b0.y, 0.0f);
        r0.z = fmaxf(acc[2] * inv + b0.z, 0.0f);
        r0.w = fmaxf(acc[3] * inv + b0.w, 0.0f);
        r1.x = fmaxf(acc[4] * inv + b1.x, 0.0f);
        r1.y = fmaxf(acc[5] * inv + b1.y, 0.0f);
        r1.z = fmaxf(acc[6] * inv + b1.z, 0.0f);
        r1.w = fmaxf(acc[7] * inv + b1.w, 0.0f);
        ((float4*)out)[(size_t)wid * 32 + ql * 2] = r0;
        ((float4*)out)[(size_t)wid * 32 + ql * 2 + 1] = r1;
    }
}

extern "C" void kernel_launch(void* const* d_in, const int* in_sizes, int n_in,
                              void* d_out, int out_size, void* d_ws, size_t ws_size,
                              hipStream_t stream) {
    const float* x = (const float*)d_in[0];
    const int* edges = (const int*)d_in[1];
    const float* W1 = (const float*)d_in[2];
    const float* att_s1 = (const float*)d_in[3];
    const float* att_d1 = (const float*)d_in[4];
    const float* b1 = (const float*)d_in[5];
    const float* W2 = (const float*)d_in[6];
    const float* att_s2 = (const float*)d_in[7];
    const float* att_d2 = (const float*)d_in[8];
    const float* b2 = (const float*)d_in[9];

    const int N = in_sizes[0] / 128;
    const int E = in_sizes[1] / 2;
    const int* e_src = edges;
    const int* e_dst = edges + E;

    char* w = (char*)d_ws;
    auto carve = [&](size_t bytes) {
        char* p = w;
        w += (bytes + 255) & ~(size_t)255;
        return p;
    };
    const int n4 = (N + 3) >> 2;
    int* counts = (int*)carve((size_t)n4 * 16);           // padded to int4
    int* offsets = (int*)carve((size_t)(N + 8) * 4);
    int* rank = (int*)carve((size_t)E * 4);
    int* csr_src = (int*)carve((size_t)E * 4);
    float* a_s = (float*)carve((size_t)N * 4);
    float* a_d = (float*)carve((size_t)N * 4);
    unsigned short* xlb = (unsigned short*)carve((size_t)N * 128 * 2);
    float* h = (float*)carve((size_t)N * 128 * 4);

    float* out = (float*)d_out;

    // --- CSR build: split kernels (proven path) ---
    k_zero4<<<(n4 + 255) / 256, 256, 0, stream>>>(counts, n4);
    bool vec_ok = ((E & 3) == 0) && ((((uintptr_t)e_dst) & 15) == 0) &&
                  ((((uintptr_t)e_src) & 15) == 0);
    if (vec_ok) {
        int qb = (E / 4 + 255) / 256;
        k_hist_rank<<<qb, 256, 0, stream>>>(e_dst, E, counts, rank);
        k_scan<<<1, 1024, 0, stream>>>(counts, offsets, N);
        k_scatter<<<qb, 256, 0, stream>>>(e_src, e_dst, rank, offsets, E, csr_src);
    } else {
        int sb = (E + 255) / 256;
        k_hist_rank_s<<<sb, 256, 0, stream>>>(e_dst, E, counts, rank);
        k_scan<<<1, 1024, 0, stream>>>(counts, offsets, N);
        k_scatter_s<<<sb, 256, 0, stream>>>(e_src, e_dst, rank, offsets, E, csr_src);
    }

    int gemm_blocks = (N + 127) / 128;
    int wave_blocks = (N * 64 + 255) / 256;

    // layer 1
    k_gemm_attn<<<gemm_blocks, 256, 0, stream>>>(x, W1, att_s1, att_d1, xlb, a_s, a_d, N);
    k_aggregate<<<wave_blocks, 256, 0, stream>>>(xlb, a_s, a_d, csr_src, offsets, b1, h, N);

    // layer 2 (xlb reused; agg1 finishes before gemm2 overwrites it)
    k_gemm_attn<<<gemm_blocks, 256, 0, stream>>>(h, W2, att_s2, att_d2, xlb, a_s, a_d, N);
    k_aggregate<<<wave_blocks, 256, 0, stream>>>(xlb, a_s, a_d, csr_src, offsets, b2, out, N);
}

// Round 10
// 181.250 us; speedup vs baseline: 2.5413x; 1.1936x over previous
//
#include <hip/hip_runtime.h>
#include <hip/hip_bf16.h>
#include <math.h>

#define NEG_SLOPE 0.2f

using bf16x8 = __attribute__((ext_vector_type(8))) short;
using f32x4 = __attribute__((ext_vector_type(4))) float;

__device__ __forceinline__ float lrelu(float v) {
    return v > 0.0f ? v : NEG_SLOPE * v;
}

__device__ __forceinline__ float wred_sum(float v) {
    #pragma unroll
    for (int d = 32; d; d >>= 1) v += __shfl_xor(v, d);
    return v;
}

__device__ __forceinline__ unsigned short f2bf(float f) {  // RNE f32->bf16
    unsigned u = __float_as_uint(f);
    return (unsigned short)((u + 0x7FFFu + ((u >> 16) & 1u)) >> 16);
}

__device__ __forceinline__ void bf8_fma(float* acc, uint4 u, float w) {
    acc[0] += w * __uint_as_float(u.x << 16);
    acc[1] += w * __uint_as_float(u.x & 0xFFFF0000u);
    acc[2] += w * __uint_as_float(u.y << 16);
    acc[3] += w * __uint_as_float(u.y & 0xFFFF0000u);
    acc[4] += w * __uint_as_float(u.z << 16);
    acc[5] += w * __uint_as_float(u.z & 0xFFFF0000u);
    acc[6] += w * __uint_as_float(u.w << 16);
    acc[7] += w * __uint_as_float(u.w & 0xFFFF0000u);
}

// ---- Split-kernel CSR build (proven path) ----
__global__ void k_zero4(int* __restrict__ p, int n4) {
    int i = blockIdx.x * blockDim.x + threadIdx.x;
    if (i < n4) ((int4*)p)[i] = make_int4(0, 0, 0, 0);
}

__global__ void k_hist_rank(const int* __restrict__ dst, int E,
                            int* __restrict__ counts, int* __restrict__ rank) {
    int i = blockIdx.x * blockDim.x + threadIdx.x;
    int base = i << 2;
    if (base + 3 < E) {
        int4 d = ((const int4*)dst)[i];
        int4 r;
        r.x = atomicAdd(&counts[d.x], 1);
        r.y = atomicAdd(&counts[d.y], 1);
        r.z = atomicAdd(&counts[d.z], 1);
        r.w = atomicAdd(&counts[d.w], 1);
        ((int4*)rank)[i] = r;
    } else {
        for (int j = base; j < E; ++j) rank[j] = atomicAdd(&counts[dst[j]], 1);
    }
}

__global__ void k_hist_rank_s(const int* __restrict__ dst, int E,
                              int* __restrict__ counts, int* __restrict__ rank) {
    int i = blockIdx.x * blockDim.x + threadIdx.x;
    if (i < E) rank[i] = atomicAdd(&counts[dst[i]], 1);
}

__global__ __launch_bounds__(1024) void k_scan(const int* __restrict__ counts,
                                               int* __restrict__ offsets, int n) {
    __shared__ int wsums[16];
    __shared__ int carry_sh;
    int tid = threadIdx.x;
    int lane = tid & 63;
    int wv = tid >> 6;
    if (tid == 0) carry_sh = 0;
    __syncthreads();
    int n4 = (n + 3) >> 2;
    for (int base = 0; base < n4; base += 1024) {
        int i = base + tid;
        int e0 = i << 2;
        int v0 = 0, v1 = 0, v2 = 0, v3 = 0;
        if (e0 + 3 < n) {
            int4 c = ((const int4*)counts)[i];
            v0 = c.x; v1 = c.y; v2 = c.z; v3 = c.w;
        } else if (e0 < n) {
            v0 = counts[e0];
            if (e0 + 1 < n) v1 = counts[e0 + 1];
            if (e0 + 2 < n) v2 = counts[e0 + 2];
        }
        int p1 = v0, p2 = p1 + v1, p3 = p2 + v2, tot = p3 + v3;
        int x = tot;
        #pragma unroll
        for (int d = 1; d < 64; d <<= 1) {
            int y = __shfl_up(x, d);
            if (lane >= d) x += y;
        }
        if (lane == 63) wsums[wv] = x;
        __syncthreads();
        if (wv == 0) {
            int s = (lane < 16) ? wsums[lane] : 0;
            #pragma unroll
            for (int d = 1; d < 16; d <<= 1) {
                int y = __shfl_up(s, d);
                if (lane >= d) s += y;
            }
            if (lane < 16) wsums[lane] = s;
        }
        __syncthreads();
        int excl = carry_sh + (wv > 0 ? wsums[wv - 1] : 0) + (x - tot);
        if (e0 + 3 < n) {
            ((int4*)offsets)[i] = make_int4(excl, excl + p1, excl + p2, excl + p3);
        } else if (e0 < n) {
            offsets[e0] = excl;
            if (e0 + 1 < n) offsets[e0 + 1] = excl + p1;
            if (e0 + 2 < n) offsets[e0 + 2] = excl + p2;
        }
        __syncthreads();
        if (tid == 0) carry_sh += wsums[15];
        __syncthreads();
    }
    if (tid == 0) offsets[n] = carry_sh;
}

__global__ void k_scatter(const int* __restrict__ src, const int* __restrict__ dst,
                          const int* __restrict__ rank, const int* __restrict__ offsets,
                          int E, int* __restrict__ csr_src) {
    int i = blockIdx.x * blockDim.x + threadIdx.x;
    int base = i << 2;
    if (base + 3 < E) {
        int4 s = ((const int4*)src)[i];
        int4 d = ((const int4*)dst)[i];
        int4 r = ((const int4*)rank)[i];
        csr_src[offsets[d.x] + r.x] = s.x;
        csr_src[offsets[d.y] + r.y] = s.y;
        csr_src[offsets[d.z] + r.z] = s.z;
        csr_src[offsets[d.w] + r.w] = s.w;
    } else {
        for (int j = base; j < E; ++j) csr_src[offsets[dst[j]] + rank[j]] = src[j];
    }
}

__global__ void k_scatter_s(const int* __restrict__ src, const int* __restrict__ dst,
                            const int* __restrict__ rank, const int* __restrict__ offsets,
                            int E, int* __restrict__ csr_src) {
    int i = blockIdx.x * blockDim.x + threadIdx.x;
    if (i < E) csr_src[offsets[dst[i]] + rank[i]] = src[i];
}

// Pre-transpose + bf16-split both weight matrices: Wt*[n][k] (n-major).
// Wh = bf16(w), Wl = bf16(w - f32(Wh)). i covers 2 x 128 x 128.
__global__ void k_wsplit(const float* __restrict__ W1, const float* __restrict__ W2,
                         unsigned short* __restrict__ h1, unsigned short* __restrict__ l1,
                         unsigned short* __restrict__ h2, unsigned short* __restrict__ l2) {
    int i = blockIdx.x * blockDim.x + threadIdx.x;  // 0..32767
    int sel = i >> 14;
    int j = i & 16383;
    int nn = j >> 7, kk = j & 127;
    const float* W = sel ? W2 : W1;
    float f = W[kk * 128 + nn];
    unsigned short h = f2bf(f);
    float hf = __uint_as_float((unsigned)h << 16);
    unsigned short lo = f2bf(f - hf);
    if (sel) { h2[j] = h; l2[j] = lo; }
    else     { h1[j] = h; l1[j] = lo; }
}

// ---------------------------------------------------------------------------
// MFMA GEMM, bf16x3 (numerically ~exact): XL = Xh*Wh + Xl*Wh + Xh*Wl.
// Orientation: compute XL^T = W^T * X^T per 128x128 tile so BOTH operand
// fragments are 8-consecutive-k bf16 b128 reads from row-major [outer][k]
// LDS tiles (XOR swizzle ((row&7)<<4) kills the 128B-stride bank conflict).
// mfma_f32_16x16x32_bf16: A row = lane&15, k = (lane>>4)*8+j; B col = lane&15
// (same k map — k-permutation uncertainty cancels since both operands use the
// identical position->k convention). C/D (m89-verified): col(lane&15) = XL
// row, row((lane>>4)*4+reg) = XL col -> lane holds 4 consecutive XL cols of
// one row = packed uint2 store, and the att_s/att_d dots use per-lane float4
// chunks + 2 shfl_xor.
// Block: 256 thr = 4 waves (wave quadrant: cols (w&1)*64, rows (w>>1)*64),
// tile 128 rows(X) x 128 cols(W), K halves of 64, 2 k-steps of 32 each.
// LDS: 4 x 16KB tiles + 2KB partials = 66KB -> 2 blocks/CU.
// ---------------------------------------------------------------------------
__global__ __launch_bounds__(256) void k_gemm_attn(const float* __restrict__ X,
                                                   const unsigned short* __restrict__ Wth,
                                                   const unsigned short* __restrict__ Wtl,
                                                   const float* __restrict__ att_s,
                                                   const float* __restrict__ att_d,
                                                   unsigned short* __restrict__ XLb,
                                                   float* __restrict__ a_s,
                                                   float* __restrict__ a_d, int n) {
    __shared__ unsigned short WhT[8192];  // [128 n][64 k] bf16, swizzled
    __shared__ unsigned short WlT[8192];
    __shared__ unsigned short XhT[8192];  // [128 m][64 k] bf16, swizzled
    __shared__ unsigned short XlT[8192];
    __shared__ float pS[2][128];
    __shared__ float pD[2][128];

    const int tid = threadIdx.x;
    const int row0 = blockIdx.x * 128;
    const int wave = tid >> 6;
    const int l = tid & 63;
    const int lr = l & 15;          // fragment row/col index
    const int lg = l >> 4;          // k-group
    const int qm = (wave & 1) * 64; // this wave's XL-col quadrant
    const int qn = (wave >> 1) * 64;// this wave's XL-row quadrant
    const unsigned swz = (unsigned)(l & 7) << 4;

    f32x4 acc[4][4];  // [mt (cols)][nt (rows)]
    #pragma unroll
    for (int a = 0; a < 4; ++a)
        #pragma unroll
        for (int b = 0; b < 4; ++b)
            acc[a][b] = (f32x4){0.f, 0.f, 0.f, 0.f};

    for (int kb = 0; kb < 128; kb += 64) {
        __syncthreads();
        // stage: X split h/l + pre-split W, both into swizzled [128][64] tiles
        #pragma unroll
        for (int it = 0; it < 4; ++it) {
            int idx = it * 256 + tid;       // 0..1023
            int m = idx >> 3;               // 0..127
            int kc = idx & 7;               // 16B chunk (8 bf16 / 8 f32 pair)
            int gr = row0 + m;
            float4 v0 = make_float4(0.f, 0.f, 0.f, 0.f), v1 = v0;
            if (gr < n) {
                const float4* Xp = (const float4*)X + (size_t)gr * 32 + (kb >> 2) + (kc << 1);
                v0 = Xp[0];
                v1 = Xp[1];
            }
            float fv[8] = {v0.x, v0.y, v0.z, v0.w, v1.x, v1.y, v1.z, v1.w};
            unsigned hp[4], lp[4];
            #pragma unroll
            for (int e = 0; e < 4; ++e) {
                unsigned short h0 = f2bf(fv[2 * e]);
                unsigned short h1 = f2bf(fv[2 * e + 1]);
                float r0 = fv[2 * e] - __uint_as_float((unsigned)h0 << 16);
                float r1 = fv[2 * e + 1] - __uint_as_float((unsigned)h1 << 16);
                hp[e] = (unsigned)h0 | ((unsigned)h1 << 16);
                lp[e] = (unsigned)f2bf(r0) | ((unsigned)f2bf(r1) << 16);
            }
            unsigned off = ((unsigned)m << 7) + ((unsigned)kc << 4);  // bytes
            unsigned so = off ^ (((unsigned)m & 7) << 4);
            *(uint4*)((char*)XhT + so) = make_uint4(hp[0], hp[1], hp[2], hp[3]);
            *(uint4*)((char*)XlT + so) = make_uint4(lp[0], lp[1], lp[2], lp[3]);
            // W tiles: row m = W col n; global Wt*[n][kb + kc*8 ..] is 16B
            size_t wsrc = (size_t)m * 128 + kb + (kc << 3);
            *(uint4*)((char*)WhT + so) = *(const uint4*)(Wth + wsrc);
            *(uint4*)((char*)WlT + so) = *(const uint4*)(Wtl + wsrc);
        }
        __syncthreads();
        #pragma unroll
        for (int ks = 0; ks < 64; ks += 32) {
            bf16x8 ah[4], al[4];
            #pragma unroll
            for (int mt = 0; mt < 4; ++mt) {
                unsigned ao = (((unsigned)(qm + mt * 16 + lr)) << 7) +
                              ((unsigned)ks << 1) + ((unsigned)lg << 4);
                ao ^= swz;
                ah[mt] = *(const bf16x8*)((const char*)WhT + ao);
                al[mt] = *(const bf16x8*)((const char*)WlT + ao);
            }
            #pragma unroll
            for (int nt = 0; nt < 4; ++nt) {
                unsigned bo = (((unsigned)(qn + nt * 16 + lr)) << 7) +
                              ((unsigned)ks << 1) + ((unsigned)lg << 4);
                bo ^= swz;
                bf16x8 bh = *(const bf16x8*)((const char*)XhT + bo);
                bf16x8 bl = *(const bf16x8*)((const char*)XlT + bo);
                #pragma unroll
                for (int mt = 0; mt < 4; ++mt) {
                    acc[mt][nt] = __builtin_amdgcn_mfma_f32_16x16x32_bf16(ah[mt], bh, acc[mt][nt], 0, 0, 0);
                    acc[mt][nt] = __builtin_amdgcn_mfma_f32_16x16x32_bf16(al[mt], bh, acc[mt][nt], 0, 0, 0);
                    acc[mt][nt] = __builtin_amdgcn_mfma_f32_16x16x32_bf16(ah[mt], bl, acc[mt][nt], 0, 0, 0);
                }
            }
        }
    }

    // fused attention dots: lane holds XL[row=qn+nt*16+lr][col=qm+mt*16+lg*4+j]
    float4 asv[4], adv[4];
    #pragma unroll
    for (int mt = 0; mt < 4; ++mt) {
        asv[mt] = *(const float4*)&att_s[qm + mt * 16 + (lg << 2)];
        adv[mt] = *(const float4*)&att_d[qm + mt * 16 + (lg << 2)];
    }
    #pragma unroll
    for (int nt = 0; nt < 4; ++nt) {
        float ps = 0.f, pd = 0.f;
        #pragma unroll
        for (int mt = 0; mt < 4; ++mt) {
            f32x4 a = acc[mt][nt];
            ps += a[0] * asv[mt].x + a[1] * asv[mt].y + a[2] * asv[mt].z + a[3] * asv[mt].w;
            pd += a[0] * adv[mt].x + a[1] * adv[mt].y + a[2] * adv[mt].z + a[3] * adv[mt].w;
        }
        ps += __shfl_xor(ps, 16); ps += __shfl_xor(ps, 32);
        pd += __shfl_xor(pd, 16); pd += __shfl_xor(pd, 32);
        if (l < 16) {
            pS[wave & 1][qn + nt * 16 + l] = ps;
            pD[wave & 1][qn + nt * 16 + l] = pd;
        }
    }
    // bf16 store of XL: 4 consecutive cols per lane -> uint2
    #pragma unroll
    for (int nt = 0; nt < 4; ++nt) {
        int grow = row0 + qn + nt * 16 + lr;
        if (grow < n) {
            #pragma unroll
            for (int mt = 0; mt < 4; ++mt) {
                int col = qm + mt * 16 + (lg << 2);
                f32x4 a = acc[mt][nt];
                unsigned p0 = ((unsigned)f2bf(a[1]) << 16) | f2bf(a[0]);
                unsigned p1 = ((unsigned)f2bf(a[3]) << 16) | f2bf(a[2]);
                *(uint2*)(XLb + (size_t)grow * 128 + col) = make_uint2(p0, p1);
            }
        }
    }
    __syncthreads();
    if (tid < 128) {
        int gr = row0 + tid;
        if (gr < n) {
            a_s[gr] = pS[0][tid] + pS[1][tid];
            a_d[gr] = pD[0][tid] + pD[1][tid];
        }
    }
}

// One wave per dst node. No-max softmax (logits bounded, exp safe in f32).
// Gather loop unrolled x2: 8 outstanding uint4 gathers/wave, branch-free body
// (clamped shfl index, OOB weight zeroed, unconditional loads).
__global__ __launch_bounds__(256) void k_aggregate(const unsigned short* __restrict__ xlb,
                                                   const float* __restrict__ a_s,
                                                   const float* __restrict__ a_d,
                                                   const int* __restrict__ csr_src,
                                                   const int* __restrict__ offsets,
                                                   const float* __restrict__ bias,
                                                   float* __restrict__ out, int n) {
    int wid = (blockIdx.x * blockDim.x + threadIdx.x) >> 6;
    int lane = threadIdx.x & 63;
    if (wid >= n) return;
    int beg = offsets[wid];
    int deg = offsets[wid + 1] - beg;
    float a_dn = a_d[wid];
    float w_self = __expf(lrelu(a_s[wid] + a_dn));

    int s_l = 0;
    float w_l = 0.0f;
    if (lane < deg) {
        s_l = csr_src[beg + lane];
        w_l = __expf(lrelu(a_s[s_l] + a_dn));
    }
    float zl = w_l;
    for (int j = 64 + lane; j < deg; j += 64) {
        int s = csr_src[beg + j];
        zl += __expf(lrelu(a_s[s] + a_dn));
    }
    float z = wred_sum(zl) + w_self;
    float inv = 1.0f / (z + 1e-16f);

    int qw = lane >> 4, ql = lane & 15;
    const uint4* xb4 = (const uint4*)xlb;  // row = 16 x uint4 (256B)
    float acc[8] = {};
    if (qw == 0) {
        uint4 u = xb4[(size_t)wid * 16 + ql];
        bf8_fma(acc, u, w_self);
    }
    int jmax = deg < 64 ? deg : 64;
    int nt = (jmax + 7) >> 3;
    for (int t = 0; t < nt; ++t) {
        int ja = (t << 3) + qw;
        int jb = ja + 4;
        int jca = ja < jmax ? ja : 0;
        int jcb = jb < jmax ? jb : 0;
        float wa = __shfl(w_l, jca);
        int sa = __shfl(s_l, jca);
        float wb = __shfl(w_l, jcb);
        int sb = __shfl(s_l, jcb);
        if (ja >= jmax) wa = 0.0f;
        if (jb >= jmax) wb = 0.0f;
        uint4 ua = xb4[(size_t)sa * 16 + ql];
        uint4 ub = xb4[(size_t)sb * 16 + ql];
        bf8_fma(acc, ua, wa);
        bf8_fma(acc, ub, wb);
    }
    for (int j = 64 + qw; j < deg; j += 4) {
        int sj = csr_src[beg + j];
        float wj = __expf(lrelu(a_s[sj] + a_dn));
        uint4 u = xb4[(size_t)sj * 16 + ql];
        bf8_fma(acc, u, wj);
    }
    #pragma unroll
    for (int k = 0; k < 8; ++k) {
        acc[k] += __shfl_xor(acc[k], 16);
        acc[k] += __shfl_xor(acc[k], 32);
    }
    if (qw == 0) {
        float4 b0 = ((const float4*)bias)[ql * 2];
        float4 b1 = ((const float4*)bias)[ql * 2 + 1];
        float4 r0, r1;
        r0.x = fmaxf(acc[0] * inv + b0.x, 0.0f);
        r0.y = fmaxf(acc[1] * inv + b0.y, 0.0f);
        r0.z = fmaxf(acc[2] * inv + b0.z, 0.0f);
        r0.w = fmaxf(acc[3] * inv + b0.w, 0.0f);
        r1.x = fmaxf(acc[4] * inv + b1.x, 0.0f);
        r1.y = fmaxf(acc[5] * inv + b1.y, 0.0f);
        r1.z = fmaxf(acc[6] * inv + b1.z, 0.0f);
        r1.w = fmaxf(acc[7] * inv + b1.w, 0.0f);
        ((float4*)out)[(size_t)wid * 32 + ql * 2] = r0;
        ((float4*)out)[(size_t)wid * 32 + ql * 2 + 1] = r1;
    }
}

extern "C" void kernel_launch(void* const* d_in, const int* in_sizes, int n_in,
                              void* d_out, int out_size, void* d_ws, size_t ws_size,
                              hipStream_t stream) {
    const float* x = (const float*)d_in[0];
    const int* edges = (const int*)d_in[1];
    const float* W1 = (const float*)d_in[2];
    const float* att_s1 = (const float*)d_in[3];
    const float* att_d1 = (const float*)d_in[4];
    const float* b1 = (const float*)d_in[5];
    const float* W2 = (const float*)d_in[6];
    const float* att_s2 = (const float*)d_in[7];
    const float* att_d2 = (const float*)d_in[8];
    const float* b2 = (const float*)d_in[9];

    const int N = in_sizes[0] / 128;
    const int E = in_sizes[1] / 2;
    const int* e_src = edges;
    const int* e_dst = edges + E;

    char* w = (char*)d_ws;
    auto carve = [&](size_t bytes) {
        char* p = w;
        w += (bytes + 255) & ~(size_t)255;
        return p;
    };
    const int n4 = (N + 3) >> 2;
    int* counts = (int*)carve((size_t)n4 * 16);
    int* offsets = (int*)carve((size_t)(N + 8) * 4);
    int* rank = (int*)carve((size_t)E * 4);
    int* csr_src = (int*)carve((size_t)E * 4);
    float* a_s = (float*)carve((size_t)N * 4);
    float* a_d = (float*)carve((size_t)N * 4);
    unsigned short* xlb = (unsigned short*)carve((size_t)N * 128 * 2);
    float* h = (float*)carve((size_t)N * 128 * 4);
    unsigned short* wth1 = (unsigned short*)carve(16384 * 2);
    unsigned short* wtl1 = (unsigned short*)carve(16384 * 2);
    unsigned short* wth2 = (unsigned short*)carve(16384 * 2);
    unsigned short* wtl2 = (unsigned short*)carve(16384 * 2);

    float* out = (float*)d_out;

    // --- W pre-transpose + bf16 split (both layers) ---
    k_wsplit<<<128, 256, 0, stream>>>(W1, W2, wth1, wtl1, wth2, wtl2);

    // --- CSR build: split kernels ---
    k_zero4<<<(n4 + 255) / 256, 256, 0, stream>>>(counts, n4);
    bool vec_ok = ((E & 3) == 0) && ((((uintptr_t)e_dst) & 15) == 0) &&
                  ((((uintptr_t)e_src) & 15) == 0);
    if (vec_ok) {
        int qb = (E / 4 + 255) / 256;
        k_hist_rank<<<qb, 256, 0, stream>>>(e_dst, E, counts, rank);
        k_scan<<<1, 1024, 0, stream>>>(counts, offsets, N);
        k_scatter<<<qb, 256, 0, stream>>>(e_src, e_dst, rank, offsets, E, csr_src);
    } else {
        int sb = (E + 255) / 256;
        k_hist_rank_s<<<sb, 256, 0, stream>>>(e_dst, E, counts, rank);
        k_scan<<<1, 1024, 0, stream>>>(counts, offsets, N);
        k_scatter_s<<<sb, 256, 0, stream>>>(e_src, e_dst, rank, offsets, E, csr_src);
    }

    int gemm_blocks = (N + 127) / 128;
    int wave_blocks = (N * 64 + 255) / 256;

    // layer 1
    k_gemm_attn<<<gemm_blocks, 256, 0, stream>>>(x, wth1, wtl1, att_s1, att_d1, xlb, a_s, a_d, N);
    k_aggregate<<<wave_blocks, 256, 0, stream>>>(xlb, a_s, a_d, csr_src, offsets, b1, h, N);

    // layer 2
    k_gemm_attn<<<gemm_blocks, 256, 0, stream>>>(h, wth2, wtl2, att_s2, att_d2, xlb, a_s, a_d, N);
    k_aggregate<<<wave_blocks, 256, 0, stream>>>(xlb, a_s, a_d, csr_src, offsets, b2, out, N);
}

// Round 11
// 177.041 us; speedup vs baseline: 2.6017x; 1.0238x over previous
//
#include <hip/hip_runtime.h>
#include <hip/hip_bf16.h>
#include <math.h>

#define NEG_SLOPE 0.2f

using bf16x8 = __attribute__((ext_vector_type(8))) short;
using f32x4 = __attribute__((ext_vector_type(4))) float;

__device__ __forceinline__ float lrelu(float v) {
    return v > 0.0f ? v : NEG_SLOPE * v;
}

__device__ __forceinline__ float wred_sum(float v) {
    #pragma unroll
    for (int d = 32; d; d >>= 1) v += __shfl_xor(v, d);
    return v;
}

__device__ __forceinline__ unsigned short f2bf(float f) {  // RNE f32->bf16
    unsigned u = __float_as_uint(f);
    return (unsigned short)((u + 0x7FFFu + ((u >> 16) & 1u)) >> 16);
}

__device__ __forceinline__ void bf8_fma(float* acc, uint4 u, float w) {
    acc[0] += w * __uint_as_float(u.x << 16);
    acc[1] += w * __uint_as_float(u.x & 0xFFFF0000u);
    acc[2] += w * __uint_as_float(u.y << 16);
    acc[3] += w * __uint_as_float(u.y & 0xFFFF0000u);
    acc[4] += w * __uint_as_float(u.z << 16);
    acc[5] += w * __uint_as_float(u.z & 0xFFFF0000u);
    acc[6] += w * __uint_as_float(u.w << 16);
    acc[7] += w * __uint_as_float(u.w & 0xFFFF0000u);
}

// Merged init: blocks [0,128) pre-transpose + bf16-split both weight
// matrices (Wt*[n][k], Wh = bf16(w), Wl = bf16(w - f32(Wh))); remaining
// blocks zero the counts histogram (saves one launch).
__global__ void k_init(const float* __restrict__ W1, const float* __restrict__ W2,
                       unsigned short* __restrict__ h1, unsigned short* __restrict__ l1,
                       unsigned short* __restrict__ h2, unsigned short* __restrict__ l2,
                       int* __restrict__ counts, int n4) {
    int b = blockIdx.x;
    if (b < 128) {
        int i = b * 256 + threadIdx.x;  // 0..32767 covers 2 x 128 x 128
        int sel = i >> 14;
        int j = i & 16383;
        int nn = j >> 7, kk = j & 127;
        const float* W = sel ? W2 : W1;
        float f = W[kk * 128 + nn];
        unsigned short h = f2bf(f);
        float hf = __uint_as_float((unsigned)h << 16);
        unsigned short lo = f2bf(f - hf);
        if (sel) { h2[j] = h; l2[j] = lo; }
        else     { h1[j] = h; l1[j] = lo; }
    } else {
        int i = (b - 128) * 256 + threadIdx.x;
        if (i < n4) ((int4*)counts)[i] = make_int4(0, 0, 0, 0);
    }
}

// Histogram + rank capture, 8 edges/thread (2 x int4) for deeper MLP in this
// latency/atomic-bound kernel. atomicAdd return value = rank within segment.
__global__ void k_hist_rank8(const int* __restrict__ dst, int E,
                             int* __restrict__ counts, int* __restrict__ rank) {
    int i = blockIdx.x * blockDim.x + threadIdx.x;
    int base = i << 3;
    if (base + 7 < E) {
        int4 d0 = ((const int4*)dst)[i * 2];
        int4 d1 = ((const int4*)dst)[i * 2 + 1];
        int4 r0, r1;
        r0.x = atomicAdd(&counts[d0.x], 1);
        r0.y = atomicAdd(&counts[d0.y], 1);
        r0.z = atomicAdd(&counts[d0.z], 1);
        r0.w = atomicAdd(&counts[d0.w], 1);
        r1.x = atomicAdd(&counts[d1.x], 1);
        r1.y = atomicAdd(&counts[d1.y], 1);
        r1.z = atomicAdd(&counts[d1.z], 1);
        r1.w = atomicAdd(&counts[d1.w], 1);
        ((int4*)rank)[i * 2] = r0;
        ((int4*)rank)[i * 2 + 1] = r1;
    } else {
        for (int j = base; j < E; ++j) rank[j] = atomicAdd(&counts[dst[j]], 1);
    }
}

__global__ void k_hist_rank_s(const int* __restrict__ dst, int E,
                              int* __restrict__ counts, int* __restrict__ rank) {
    int i = blockIdx.x * blockDim.x + threadIdx.x;
    if (i < E) rank[i] = atomicAdd(&counts[dst[i]], 1);
}

// Single-block exclusive scan, 4 elems/thread, SOFTWARE-PREFETCHED: tile
// t+1's int4 load issues before tile t's shfl/sync chain (hides ~600cy
// load latency that dominated this kernel). counts is fully zeroed incl.
// int4 padding, so no scalar tail is needed; padded offsets land in the
// padded region of the offsets buffer with value E (harmless/correct).
__global__ __launch_bounds__(1024) void k_scan(const int* __restrict__ counts,
                                               int* __restrict__ offsets, int n) {
    __shared__ int wsums[16];
    __shared__ int carry_sh;
    int tid = threadIdx.x;
    int lane = tid & 63;
    int wv = tid >> 6;
    if (tid == 0) carry_sh = 0;
    int n4 = (n + 3) >> 2;
    int4 c = (tid < n4) ? ((const int4*)counts)[tid] : make_int4(0, 0, 0, 0);
    __syncthreads();
    for (int base = 0; base < n4; base += 1024) {
        int i = base + tid;
        int inx = i + 1024;
        int4 cn = (inx < n4) ? ((const int4*)counts)[inx] : make_int4(0, 0, 0, 0);
        int p1 = c.x, p2 = p1 + c.y, p3 = p2 + c.z, tot = p3 + c.w;
        int x = tot;
        #pragma unroll
        for (int d = 1; d < 64; d <<= 1) {
            int y = __shfl_up(x, d);
            if (lane >= d) x += y;
        }
        if (lane == 63) wsums[wv] = x;
        __syncthreads();
        if (wv == 0) {
            int s = (lane < 16) ? wsums[lane] : 0;
            #pragma unroll
            for (int d = 1; d < 16; d <<= 1) {
                int y = __shfl_up(s, d);
                if (lane >= d) s += y;
            }
            if (lane < 16) wsums[lane] = s;
        }
        __syncthreads();
        int excl = carry_sh + (wv > 0 ? wsums[wv - 1] : 0) + (x - tot);
        if (i < n4)
            ((int4*)offsets)[i] = make_int4(excl, excl + p1, excl + p2, excl + p3);
        __syncthreads();
        if (tid == 0) carry_sh += wsums[15];
        c = cn;
        __syncthreads();
    }
    if (tid == 0) offsets[n] = carry_sh;
}

// Atomic-free scatter, 8 edges/thread: position = offsets[dst] + rank.
__global__ void k_scatter8(const int* __restrict__ src, const int* __restrict__ dst,
                           const int* __restrict__ rank, const int* __restrict__ offsets,
                           int E, int* __restrict__ csr_src) {
    int i = blockIdx.x * blockDim.x + threadIdx.x;
    int base = i << 3;
    if (base + 7 < E) {
        int4 s0 = ((const int4*)src)[i * 2];
        int4 s1 = ((const int4*)src)[i * 2 + 1];
        int4 d0 = ((const int4*)dst)[i * 2];
        int4 d1 = ((const int4*)dst)[i * 2 + 1];
        int4 r0 = ((const int4*)rank)[i * 2];
        int4 r1 = ((const int4*)rank)[i * 2 + 1];
        csr_src[offsets[d0.x] + r0.x] = s0.x;
        csr_src[offsets[d0.y] + r0.y] = s0.y;
        csr_src[offsets[d0.z] + r0.z] = s0.z;
        csr_src[offsets[d0.w] + r0.w] = s0.w;
        csr_src[offsets[d1.x] + r1.x] = s1.x;
        csr_src[offsets[d1.y] + r1.y] = s1.y;
        csr_src[offsets[d1.z] + r1.z] = s1.z;
        csr_src[offsets[d1.w] + r1.w] = s1.w;
    } else {
        for (int j = base; j < E; ++j) csr_src[offsets[dst[j]] + rank[j]] = src[j];
    }
}

__global__ void k_scatter_s(const int* __restrict__ src, const int* __restrict__ dst,
                            const int* __restrict__ rank, const int* __restrict__ offsets,
                            int E, int* __restrict__ csr_src) {
    int i = blockIdx.x * blockDim.x + threadIdx.x;
    if (i < E) csr_src[offsets[dst[i]] + rank[i]] = src[i];
}

// ---------------------------------------------------------------------------
// MFMA GEMM, bf16x3 (numerically ~exact): XL = Xh*Wh + Xl*Wh + Xh*Wl.
// XL^T = W^T * X^T per 128x128 tile; both operand fragments are
// 8-consecutive-k bf16 b128 reads from row-major [outer][k] LDS tiles
// (XOR swizzle ((row&7)<<4)). C/D: col(lane&15)=XL row,
// row((lane>>4)*4+reg)=XL col -> packed uint2 stores + cheap fused dots.
// Block: 256 thr = 4 waves, tile 128x128, K halves of 64. 66KB LDS.
// ---------------------------------------------------------------------------
__global__ __launch_bounds__(256) void k_gemm_attn(const float* __restrict__ X,
                                                   const unsigned short* __restrict__ Wth,
                                                   const unsigned short* __restrict__ Wtl,
                                                   const float* __restrict__ att_s,
                                                   const float* __restrict__ att_d,
                                                   unsigned short* __restrict__ XLb,
                                                   float* __restrict__ a_s,
                                                   float* __restrict__ a_d, int n) {
    __shared__ unsigned short WhT[8192];  // [128 n][64 k] bf16, swizzled
    __shared__ unsigned short WlT[8192];
    __shared__ unsigned short XhT[8192];  // [128 m][64 k] bf16, swizzled
    __shared__ unsigned short XlT[8192];
    __shared__ float pS[2][128];
    __shared__ float pD[2][128];

    const int tid = threadIdx.x;
    const int row0 = blockIdx.x * 128;
    const int wave = tid >> 6;
    const int l = tid & 63;
    const int lr = l & 15;          // fragment row/col index
    const int lg = l >> 4;          // k-group
    const int qm = (wave & 1) * 64; // this wave's XL-col quadrant
    const int qn = (wave >> 1) * 64;// this wave's XL-row quadrant
    const unsigned swz = (unsigned)(l & 7) << 4;

    f32x4 acc[4][4];  // [mt (cols)][nt (rows)]
    #pragma unroll
    for (int a = 0; a < 4; ++a)
        #pragma unroll
        for (int b = 0; b < 4; ++b)
            acc[a][b] = (f32x4){0.f, 0.f, 0.f, 0.f};

    for (int kb = 0; kb < 128; kb += 64) {
        __syncthreads();
        #pragma unroll
        for (int it = 0; it < 4; ++it) {
            int idx = it * 256 + tid;       // 0..1023
            int m = idx >> 3;               // 0..127
            int kc = idx & 7;               // 16B chunk
            int gr = row0 + m;
            float4 v0 = make_float4(0.f, 0.f, 0.f, 0.f), v1 = v0;
            if (gr < n) {
                const float4* Xp = (const float4*)X + (size_t)gr * 32 + (kb >> 2) + (kc << 1);
                v0 = Xp[0];
                v1 = Xp[1];
            }
            float fv[8] = {v0.x, v0.y, v0.z, v0.w, v1.x, v1.y, v1.z, v1.w};
            unsigned hp[4], lp[4];
            #pragma unroll
            for (int e = 0; e < 4; ++e) {
                unsigned short h0 = f2bf(fv[2 * e]);
                unsigned short h1 = f2bf(fv[2 * e + 1]);
                float r0 = fv[2 * e] - __uint_as_float((unsigned)h0 << 16);
                float r1 = fv[2 * e + 1] - __uint_as_float((unsigned)h1 << 16);
                hp[e] = (unsigned)h0 | ((unsigned)h1 << 16);
                lp[e] = (unsigned)f2bf(r0) | ((unsigned)f2bf(r1) << 16);
            }
            unsigned off = ((unsigned)m << 7) + ((unsigned)kc << 4);  // bytes
            unsigned so = off ^ (((unsigned)m & 7) << 4);
            *(uint4*)((char*)XhT + so) = make_uint4(hp[0], hp[1], hp[2], hp[3]);
            *(uint4*)((char*)XlT + so) = make_uint4(lp[0], lp[1], lp[2], lp[3]);
            size_t wsrc = (size_t)m * 128 + kb + (kc << 3);
            *(uint4*)((char*)WhT + so) = *(const uint4*)(Wth + wsrc);
            *(uint4*)((char*)WlT + so) = *(const uint4*)(Wtl + wsrc);
        }
        __syncthreads();
        #pragma unroll
        for (int ks = 0; ks < 64; ks += 32) {
            bf16x8 ah[4], al[4];
            #pragma unroll
            for (int mt = 0; mt < 4; ++mt) {
                unsigned ao = (((unsigned)(qm + mt * 16 + lr)) << 7) +
                              ((unsigned)ks << 1) + ((unsigned)lg << 4);
                ao ^= swz;
                ah[mt] = *(const bf16x8*)((const char*)WhT + ao);
                al[mt] = *(const bf16x8*)((const char*)WlT + ao);
            }
            #pragma unroll
            for (int nt = 0; nt < 4; ++nt) {
                unsigned bo = (((unsigned)(qn + nt * 16 + lr)) << 7) +
                              ((unsigned)ks << 1) + ((unsigned)lg << 4);
                bo ^= swz;
                bf16x8 bh = *(const bf16x8*)((const char*)XhT + bo);
                bf16x8 bl = *(const bf16x8*)((const char*)XlT + bo);
                #pragma unroll
                for (int mt = 0; mt < 4; ++mt) {
                    acc[mt][nt] = __builtin_amdgcn_mfma_f32_16x16x32_bf16(ah[mt], bh, acc[mt][nt], 0, 0, 0);
                    acc[mt][nt] = __builtin_amdgcn_mfma_f32_16x16x32_bf16(al[mt], bh, acc[mt][nt], 0, 0, 0);
                    acc[mt][nt] = __builtin_amdgcn_mfma_f32_16x16x32_bf16(ah[mt], bl, acc[mt][nt], 0, 0, 0);
                }
            }
        }
    }

    // fused attention dots: lane holds XL[row=qn+nt*16+lr][col=qm+mt*16+lg*4+j]
    float4 asv[4], adv[4];
    #pragma unroll
    for (int mt = 0; mt < 4; ++mt) {
        asv[mt] = *(const float4*)&att_s[qm + mt * 16 + (lg << 2)];
        adv[mt] = *(const float4*)&att_d[qm + mt * 16 + (lg << 2)];
    }
    #pragma unroll
    for (int nt = 0; nt < 4; ++nt) {
        float ps = 0.f, pd = 0.f;
        #pragma unroll
        for (int mt = 0; mt < 4; ++mt) {
            f32x4 a = acc[mt][nt];
            ps += a[0] * asv[mt].x + a[1] * asv[mt].y + a[2] * asv[mt].z + a[3] * asv[mt].w;
            pd += a[0] * adv[mt].x + a[1] * adv[mt].y + a[2] * adv[mt].z + a[3] * adv[mt].w;
        }
        ps += __shfl_xor(ps, 16); ps += __shfl_xor(ps, 32);
        pd += __shfl_xor(pd, 16); pd += __shfl_xor(pd, 32);
        if (l < 16) {
            pS[wave & 1][qn + nt * 16 + l] = ps;
            pD[wave & 1][qn + nt * 16 + l] = pd;
        }
    }
    #pragma unroll
    for (int nt = 0; nt < 4; ++nt) {
        int grow = row0 + qn + nt * 16 + lr;
        if (grow < n) {
            #pragma unroll
            for (int mt = 0; mt < 4; ++mt) {
                int col = qm + mt * 16 + (lg << 2);
                f32x4 a = acc[mt][nt];
                unsigned p0 = ((unsigned)f2bf(a[1]) << 16) | f2bf(a[0]);
                unsigned p1 = ((unsigned)f2bf(a[3]) << 16) | f2bf(a[2]);
                *(uint2*)(XLb + (size_t)grow * 128 + col) = make_uint2(p0, p1);
            }
        }
    }
    __syncthreads();
    if (tid < 128) {
        int gr = row0 + tid;
        if (gr < n) {
            a_s[gr] = pS[0][tid] + pS[1][tid];
            a_d[gr] = pD[0][tid] + pD[1][tid];
        }
    }
}

// One wave per dst node. No-max softmax (logits bounded, exp safe in f32).
// Gather loop unrolled x2: 8 outstanding uint4 gathers/wave, branch-free body
// (clamped shfl index, OOB weight zeroed, unconditional loads).
__global__ __launch_bounds__(256) void k_aggregate(const unsigned short* __restrict__ xlb,
                                                   const float* __restrict__ a_s,
                                                   const float* __restrict__ a_d,
                                                   const int* __restrict__ csr_src,
                                                   const int* __restrict__ offsets,
                                                   const float* __restrict__ bias,
                                                   float* __restrict__ out, int n) {
    int wid = (blockIdx.x * blockDim.x + threadIdx.x) >> 6;
    int lane = threadIdx.x & 63;
    if (wid >= n) return;
    int beg = offsets[wid];
    int deg = offsets[wid + 1] - beg;
    float a_dn = a_d[wid];
    float w_self = __expf(lrelu(a_s[wid] + a_dn));

    int s_l = 0;
    float w_l = 0.0f;
    if (lane < deg) {
        s_l = csr_src[beg + lane];
        w_l = __expf(lrelu(a_s[s_l] + a_dn));
    }
    float zl = w_l;
    for (int j = 64 + lane; j < deg; j += 64) {
        int s = csr_src[beg + j];
        zl += __expf(lrelu(a_s[s] + a_dn));
    }
    float z = wred_sum(zl) + w_self;
    float inv = 1.0f / (z + 1e-16f);

    int qw = lane >> 4, ql = lane & 15;
    const uint4* xb4 = (const uint4*)xlb;  // row = 16 x uint4 (256B)
    float acc[8] = {};
    if (qw == 0) {
        uint4 u = xb4[(size_t)wid * 16 + ql];
        bf8_fma(acc, u, w_self);
    }
    int jmax = deg < 64 ? deg : 64;
    int nt = (jmax + 7) >> 3;
    for (int t = 0; t < nt; ++t) {
        int ja = (t << 3) + qw;
        int jb = ja + 4;
        int jca = ja < jmax ? ja : 0;
        int jcb = jb < jmax ? jb : 0;
        float wa = __shfl(w_l, jca);
        int sa = __shfl(s_l, jca);
        float wb = __shfl(w_l, jcb);
        int sb = __shfl(s_l, jcb);
        if (ja >= jmax) wa = 0.0f;
        if (jb >= jmax) wb = 0.0f;
        uint4 ua = xb4[(size_t)sa * 16 + ql];
        uint4 ub = xb4[(size_t)sb * 16 + ql];
        bf8_fma(acc, ua, wa);
        bf8_fma(acc, ub, wb);
    }
    for (int j = 64 + qw; j < deg; j += 4) {
        int sj = csr_src[beg + j];
        float wj = __expf(lrelu(a_s[sj] + a_dn));
        uint4 u = xb4[(size_t)sj * 16 + ql];
        bf8_fma(acc, u, wj);
    }
    #pragma unroll
    for (int k = 0; k < 8; ++k) {
        acc[k] += __shfl_xor(acc[k], 16);
        acc[k] += __shfl_xor(acc[k], 32);
    }
    if (qw == 0) {
        float4 b0 = ((const float4*)bias)[ql * 2];
        float4 b1 = ((const float4*)bias)[ql * 2 + 1];
        float4 r0, r1;
        r0.x = fmaxf(acc[0] * inv + b0.x, 0.0f);
        r0.y = fmaxf(acc[1] * inv + b0.y, 0.0f);
        r0.z = fmaxf(acc[2] * inv + b0.z, 0.0f);
        r0.w = fmaxf(acc[3] * inv + b0.w, 0.0f);
        r1.x = fmaxf(acc[4] * inv + b1.x, 0.0f);
        r1.y = fmaxf(acc[5] * inv + b1.y, 0.0f);
        r1.z = fmaxf(acc[6] * inv + b1.z, 0.0f);
        r1.w = fmaxf(acc[7] * inv + b1.w, 0.0f);
        ((float4*)out)[(size_t)wid * 32 + ql * 2] = r0;
        ((float4*)out)[(size_t)wid * 32 + ql * 2 + 1] = r1;
    }
}

extern "C" void kernel_launch(void* const* d_in, const int* in_sizes, int n_in,
                              void* d_out, int out_size, void* d_ws, size_t ws_size,
                              hipStream_t stream) {
    const float* x = (const float*)d_in[0];
    const int* edges = (const int*)d_in[1];
    const float* W1 = (const float*)d_in[2];
    const float* att_s1 = (const float*)d_in[3];
    const float* att_d1 = (const float*)d_in[4];
    const float* b1 = (const float*)d_in[5];
    const float* W2 = (const float*)d_in[6];
    const float* att_s2 = (const float*)d_in[7];
    const float* att_d2 = (const float*)d_in[8];
    const float* b2 = (const float*)d_in[9];

    const int N = in_sizes[0] / 128;
    const int E = in_sizes[1] / 2;
    const int* e_src = edges;
    const int* e_dst = edges + E;

    char* w = (char*)d_ws;
    auto carve = [&](size_t bytes) {
        char* p = w;
        w += (bytes + 255) & ~(size_t)255;
        return p;
    };
    const int n4 = (N + 3) >> 2;
    int* counts = (int*)carve((size_t)n4 * 16);
    int* offsets = (int*)carve((size_t)(N + 8) * 4);
    int* rank = (int*)carve((size_t)E * 4);
    int* csr_src = (int*)carve((size_t)E * 4);
    float* a_s = (float*)carve((size_t)N * 4);
    float* a_d = (float*)carve((size_t)N * 4);
    unsigned short* xlb = (unsigned short*)carve((size_t)N * 128 * 2);
    float* h = (float*)carve((size_t)N * 128 * 4);
    unsigned short* wth1 = (unsigned short*)carve(16384 * 2);
    unsigned short* wtl1 = (unsigned short*)carve(16384 * 2);
    unsigned short* wth2 = (unsigned short*)carve(16384 * 2);
    unsigned short* wtl2 = (unsigned short*)carve(16384 * 2);

    float* out = (float*)d_out;

    // --- init: W split (blocks 0..127) + counts zero (rest), one launch ---
    int init_blocks = 128 + (n4 + 255) / 256;
    k_init<<<init_blocks, 256, 0, stream>>>(W1, W2, wth1, wtl1, wth2, wtl2, counts, n4);

    // --- CSR build ---
    bool vec_ok = ((((uintptr_t)e_dst) & 15) == 0) && ((((uintptr_t)e_src) & 15) == 0);
    if (vec_ok) {
        int qb = ((E + 7) / 8 + 255) / 256;
        k_hist_rank8<<<qb, 256, 0, stream>>>(e_dst, E, counts, rank);
        k_scan<<<1, 1024, 0, stream>>>(counts, offsets, N);
        k_scatter8<<<qb, 256, 0, stream>>>(e_src, e_dst, rank, offsets, E, csr_src);
    } else {
        int sb = (E + 255) / 256;
        k_hist_rank_s<<<sb, 256, 0, stream>>>(e_dst, E, counts, rank);
        k_scan<<<1, 1024, 0, stream>>>(counts, offsets, N);
        k_scatter_s<<<sb, 256, 0, stream>>>(e_src, e_dst, rank, offsets, E, csr_src);
    }

    int gemm_blocks = (N + 127) / 128;
    int wave_blocks = (N * 64 + 255) / 256;

    // layer 1
    k_gemm_attn<<<gemm_blocks, 256, 0, stream>>>(x, wth1, wtl1, att_s1, att_d1, xlb, a_s, a_d, N);
    k_aggregate<<<wave_blocks, 256, 0, stream>>>(xlb, a_s, a_d, csr_src, offsets, b1, h, N);

    // layer 2
    k_gemm_attn<<<gemm_blocks, 256, 0, stream>>>(h, wth2, wtl2, att_s2, att_d2, xlb, a_s, a_d, N);
    k_aggregate<<<wave_blocks, 256, 0, stream>>>(xlb, a_s, a_d, csr_src, offsets, b2, out, N);
}